// Round 2
// baseline (179.848 us; speedup 1.0000x reference)
//
#include <hip/hip_runtime.h>
#include <hip/hip_bf16.h>
#include <stdint.h>

#define S_LEN 2048
#define D_DIM 1024
#define P_DIM 256
#define NQ_   8192
#define M_TOT 16384  // B*S

typedef __attribute__((ext_vector_type(4))) float  f32x4;
typedef __attribute__((ext_vector_type(8))) __bf16 bf16x8;
typedef __attribute__((ext_vector_type(4))) __bf16 bf16x4;

// ---------------- Kernel 0: W [1024][256] f32 -> WT [256][1024] bf16 ----------
__global__ __launch_bounds__(1024) void wt_kernel(const float* __restrict__ W,
                                                  __bf16* __restrict__ WT) {
    __shared__ __bf16 tile[32][33];  // +1 pad breaks bank conflicts
    const int k0 = blockIdx.x * 32;
    const int n0 = blockIdx.y * 32;
    const int tx = threadIdx.x, ty = threadIdx.y;
    tile[ty][tx] = (__bf16)W[(k0 + ty) * P_DIM + (n0 + tx)];
    __syncthreads();
    WT[(n0 + ty) * D_DIM + (k0 + tx)] = tile[tx][ty];
}

// ---------------- Kernel 1: H = A @ W + b  -----------------------------------
// Barrier-free, LDS-free MFMA GEMM. Block = 256 threads = 4 waves, covers
// 32 rows x 256 cols. Wave w takes cols [w*64, w*64+64): 2 m-tiles x 4 n-tiles
// of 16x16x32 bf16 MFMA. A fragments: 2x global_load_dwordx4 + cvt per tile.
// B fragments: 1x global_load_dwordx4 per tile (WT is [n][k], k-contiguous).
// Register double-buffer: prefetch K-step k+32 before MFMAs of step k.
// grid = 512 -> 2 blocks/CU, 8 waves/CU, no __syncthreads anywhere.
__global__ __launch_bounds__(256) void gemm_kernel(const float*  __restrict__ A,
                                                   const __bf16* __restrict__ WT,
                                                   const float*  __restrict__ bias,
                                                   float*        __restrict__ H) {
    const int tid = threadIdx.x;
    const int w   = tid >> 6;   // wave 0..3 -> n-quarter
    const int l   = tid & 63;
    const int lm  = l & 15;     // row (A) / col (B) within 16-tile
    const int q   = l >> 4;     // quad -> k-offset q*8

    const int m0 = blockIdx.x * 32;

    const float*  pa = A  + (size_t)(m0 + lm) * D_DIM + q * 8;
    const __bf16* pb = WT + (size_t)(w * 64 + lm) * D_DIM + q * 8;

    f32x4 acc[2][4] = {};

    float4 ra[2][2];   // current raw A  [m-tile][half]
    bf16x8 rb[4];      // current B frags [n-tile]

    // ---- preload k0 = 0
    #pragma unroll
    for (int mi = 0; mi < 2; ++mi) {
        ra[mi][0] = *(const float4*)(pa + mi * 16 * D_DIM);
        ra[mi][1] = *(const float4*)(pa + mi * 16 * D_DIM + 4);
    }
    #pragma unroll
    for (int ni = 0; ni < 4; ++ni)
        rb[ni] = *(const bf16x8*)(pb + ni * 16 * D_DIM);

    #pragma unroll 4
    for (int k0 = 0; k0 < D_DIM - 32; k0 += 32) {
        const int kn = k0 + 32;
        // ---- issue next step's loads first (stay in flight through the MFMAs)
        float4 na[2][2];
        bf16x8 nb[4];
        #pragma unroll
        for (int mi = 0; mi < 2; ++mi) {
            na[mi][0] = *(const float4*)(pa + mi * 16 * D_DIM + kn);
            na[mi][1] = *(const float4*)(pa + mi * 16 * D_DIM + kn + 4);
        }
        #pragma unroll
        for (int ni = 0; ni < 4; ++ni)
            nb[ni] = *(const bf16x8*)(pb + ni * 16 * D_DIM + kn);

        // ---- convert current A to bf16 fragments
        bf16x8 af[2];
        #pragma unroll
        for (int mi = 0; mi < 2; ++mi) {
            af[mi][0] = (__bf16)ra[mi][0].x; af[mi][1] = (__bf16)ra[mi][0].y;
            af[mi][2] = (__bf16)ra[mi][0].z; af[mi][3] = (__bf16)ra[mi][0].w;
            af[mi][4] = (__bf16)ra[mi][1].x; af[mi][5] = (__bf16)ra[mi][1].y;
            af[mi][6] = (__bf16)ra[mi][1].z; af[mi][7] = (__bf16)ra[mi][1].w;
        }
        // ---- 8 MFMAs
        #pragma unroll
        for (int mi = 0; mi < 2; ++mi)
            #pragma unroll
            for (int ni = 0; ni < 4; ++ni)
                acc[mi][ni] = __builtin_amdgcn_mfma_f32_16x16x32_bf16(
                    af[mi], rb[ni], acc[mi][ni], 0, 0, 0);
        // ---- rotate
        #pragma unroll
        for (int mi = 0; mi < 2; ++mi) { ra[mi][0] = na[mi][0]; ra[mi][1] = na[mi][1]; }
        #pragma unroll
        for (int ni = 0; ni < 4; ++ni) rb[ni] = nb[ni];
    }

    // ---- last K-step (k0 = D_DIM-32), no prefetch
    {
        bf16x8 af[2];
        #pragma unroll
        for (int mi = 0; mi < 2; ++mi) {
            af[mi][0] = (__bf16)ra[mi][0].x; af[mi][1] = (__bf16)ra[mi][0].y;
            af[mi][2] = (__bf16)ra[mi][0].z; af[mi][3] = (__bf16)ra[mi][0].w;
            af[mi][4] = (__bf16)ra[mi][1].x; af[mi][5] = (__bf16)ra[mi][1].y;
            af[mi][6] = (__bf16)ra[mi][1].z; af[mi][7] = (__bf16)ra[mi][1].w;
        }
        #pragma unroll
        for (int mi = 0; mi < 2; ++mi)
            #pragma unroll
            for (int ni = 0; ni < 4; ++ni)
                acc[mi][ni] = __builtin_amdgcn_mfma_f32_16x16x32_bf16(
                    af[mi], rb[ni], acc[mi][ni], 0, 0, 0);
    }

    // ---- epilogue: D layout row = q*4 + r, col = lane&15
    #pragma unroll
    for (int ni = 0; ni < 4; ++ni) {
        const int col = w * 64 + ni * 16 + lm;
        const float bv = bias[col];
        #pragma unroll
        for (int mi = 0; mi < 2; ++mi) {
            const int rbase = m0 + mi * 16 + q * 4;
            #pragma unroll
            for (int r = 0; r < 4; ++r)
                H[(size_t)(rbase + r) * P_DIM + col] = acc[mi][ni][r] + bv;
        }
    }
}

// ---------------- Kernel 2: span gather -------------------------------------
__global__ __launch_bounds__(256) void gather_kernel(const float* __restrict__ H,
                                                     const int* __restrict__ s1,
                                                     const int* __restrict__ e1,
                                                     const int* __restrict__ qb,
                                                     const int* __restrict__ s2,
                                                     const int* __restrict__ e2,
                                                     float* __restrict__ out) {
    const int qi  = blockIdx.x;
    const int t   = threadIdx.x;
    const int b   = qb[qi];
    const int set = t >> 7;            // 0 -> (s1,e1), 1 -> (s2,e2)
    const int rem = t & 127;
    const int half = rem >> 6;         // 0 -> start row, 1 -> end row
    const int c4  = (rem & 63) << 2;   // float4 column offset

    const int s = set ? s2[qi] : s1[qi];
    const int e = set ? e2[qi] : e1[qi];

    float4 v = make_float4(0.f, 0.f, 0.f, 0.f);
    if (e >= s) {
        const int ridx = half ? e : s;
        v = *(const float4*)(H + ((size_t)b * S_LEN + ridx) * P_DIM + c4);
    }
    *(float4*)(out + (size_t)set * (NQ_ * 512) + (size_t)qi * 512 + half * 256 + c4) = v;
}

// ---------------- launch ------------------------------------------------------
extern "C" void kernel_launch(void* const* d_in, const int* in_sizes, int n_in,
                              void* d_out, int out_size, void* d_ws, size_t ws_size,
                              hipStream_t stream) {
    const float* A    = (const float*)d_in[1];   // encoded_input [8,2048,1024]
    const int*   s1   = (const int*)  d_in[2];
    const int*   e1   = (const int*)  d_in[3];
    const int*   qb   = (const int*)  d_in[4];
    const int*   s2   = (const int*)  d_in[5];
    const int*   e2   = (const int*)  d_in[6];
    const float* W    = (const float*)d_in[7];   // [1024,256]
    const float* bias = (const float*)d_in[8];   // [256]
    float*       out  = (float*)d_out;           // res1 ++ res2, 8388608 floats

    __bf16* WT = (__bf16*)d_ws;                      // 512 KB
    float*  H  = (float*)((char*)d_ws + (1 << 20));  // 16 MB at +1MB

    wt_kernel    <<<dim3(32, 8), dim3(32, 32), 0, stream>>>(W, WT);
    gemm_kernel  <<<dim3(M_TOT / 32), dim3(256), 0, stream>>>(A, WT, bias, H);
    gather_kernel<<<dim3(NQ_), dim3(256), 0, stream>>>(H, s1, e1, qb, s2, e2, out);
}